// Round 5
// baseline (1290.194 us; speedup 1.0000x reference)
//
#include <hip/hip_runtime.h>

#define HD 64  // hidden dim

// ---------------------------------------------------------------------------
// zero-fill ints
// ---------------------------------------------------------------------------
__global__ void __launch_bounds__(256) zero_int_kernel(int* p, long n) {
    long i = blockIdx.x * (long)blockDim.x + threadIdx.x;
    long stride = (long)gridDim.x * blockDim.x;
    for (; i < n; i += stride) p[i] = 0;
}

// ---------------------------------------------------------------------------
// histogram of dst into cnt
// ---------------------------------------------------------------------------
__global__ void __launch_bounds__(256) hist_kernel(const int* __restrict__ dst,
                                                   int* __restrict__ cnt, long E) {
    long i = blockIdx.x * (long)blockDim.x + threadIdx.x;
    long stride = (long)gridDim.x * blockDim.x;
    for (; i < E; i += stride) atomicAdd(&cnt[dst[i]], 1);
}

// ---------------------------------------------------------------------------
// scan stage 1: per-256-chunk sums
// ---------------------------------------------------------------------------
__global__ void __launch_bounds__(256) blocksum_kernel(const int* __restrict__ cnt,
                                                       int* __restrict__ bsum, int N) {
    int i = blockIdx.x * 256 + threadIdx.x;
    int v = (i < N) ? cnt[i] : 0;
    #pragma unroll
    for (int off = 32; off; off >>= 1) v += __shfl_down(v, off, 64);
    __shared__ int s[4];
    if ((threadIdx.x & 63) == 0) s[threadIdx.x >> 6] = v;
    __syncthreads();
    if (threadIdx.x == 0) bsum[blockIdx.x] = s[0] + s[1] + s[2] + s[3];
}

// ---------------------------------------------------------------------------
// scan stage 2: single block scans the (<=512) chunk sums -> exclusive bpre
// ---------------------------------------------------------------------------
__global__ void __launch_bounds__(512) scan2_kernel(const int* __restrict__ bsum,
                                                    int* __restrict__ bpre,
                                                    int* __restrict__ offs,
                                                    int nb, int N, int E) {
    __shared__ int s[512];
    int tid = threadIdx.x;
    int v = (tid < nb) ? bsum[tid] : 0;
    s[tid] = v;
    __syncthreads();
    for (int off = 1; off < 512; off <<= 1) {
        int add = (tid >= off) ? s[tid - off] : 0;
        __syncthreads();
        s[tid] += add;
        __syncthreads();
    }
    if (tid < nb) bpre[tid] = s[tid] - v;  // exclusive
    if (tid == 0) offs[N] = E;
}

// ---------------------------------------------------------------------------
// scan stage 3: per-chunk exclusive scan + chunk prefix -> offs, cursor
// ---------------------------------------------------------------------------
__global__ void __launch_bounds__(256) scan3_kernel(const int* __restrict__ cnt,
                                                    const int* __restrict__ bpre,
                                                    int* __restrict__ offs,
                                                    int* __restrict__ cursor, int N) {
    __shared__ int s[256];
    int tid = threadIdx.x;
    int i = blockIdx.x * 256 + tid;
    int v = (i < N) ? cnt[i] : 0;
    s[tid] = v;
    __syncthreads();
    for (int off = 1; off < 256; off <<= 1) {
        int add = (tid >= off) ? s[tid - off] : 0;
        __syncthreads();
        s[tid] += add;
        __syncthreads();
    }
    if (i < N) {
        int excl = s[tid] - v + bpre[blockIdx.x];
        offs[i] = excl;
        cursor[i] = excl;
    }
}

// ---------------------------------------------------------------------------
// fill permutation: for each edge, place its id and src into CSR slot
// ---------------------------------------------------------------------------
__global__ void __launch_bounds__(256) fill_kernel(const int* __restrict__ src,
                                                   const int* __restrict__ dst,
                                                   int* __restrict__ cursor,
                                                   int* __restrict__ perm,
                                                   int* __restrict__ sp, long E) {
    long i = blockIdx.x * (long)blockDim.x + threadIdx.x;
    long stride = (long)gridDim.x * blockDim.x;
    for (; i < E; i += stride) {
        int d = dst[i];
        int p = atomicAdd(&cursor[d], 1);
        perm[p] = (int)i;
        sp[p]   = src[i];
    }
}

// ---------------------------------------------------------------------------
// permute edge_attr into CSR slot order: eap[j] = ea[perm[j]]
// One-time 820MB pass (random full-line reads, coalesced writes) that makes
// all 3 layers read edge data as a pure sequential stream.
// Wave handles 8 slots per iteration (2 per edge-group) so ~512B of row
// loads are in flight per wave before the stores need them.
// ---------------------------------------------------------------------------
__global__ void __launch_bounds__(256, 8) permute_ea_kernel(
    const int* __restrict__ perm, const float* __restrict__ ea,
    float* __restrict__ eap, long E)
{
    int tid  = threadIdx.x;
    int wv   = tid >> 6;        // 0..3
    int lane = tid & 63;
    int eg   = lane >> 4;       // 0..3
    int cq   = (lane & 15) * 4; // channel-quad base

    long nw = (long)gridDim.x * 4;       // total waves
    for (long j0 = ((long)blockIdx.x * 4 + wv) * 8; j0 < E; j0 += nw * 8) {
        long ja = j0 + eg;
        long jb = j0 + 4 + eg;
        bool va = ja < E, vb = jb < E;
        int ia = va ? perm[ja] : 0;
        int ib = vb ? perm[jb] : 0;
        float4 ra, rb;
        if (va) ra = *(const float4*)(ea + (long)ia * HD + cq);
        if (vb) rb = *(const float4*)(ea + (long)ib * HD + cq);
        if (va) *(float4*)(eap + ja * HD + cq) = ra;
        if (vb) *(float4*)(eap + jb * HD + cq) = rb;
    }
}

// ---------------------------------------------------------------------------
// node init: h = relu([emb[z], t] @ rw1 + rb1) @ rw2 + rb2
// (exact round-0 verified version: one node per wave, per-wave LDS slices)
// ---------------------------------------------------------------------------
__global__ void __launch_bounds__(512, 6) node_init_kernel(
    const int* __restrict__ z, const float* __restrict__ t,
    const float* __restrict__ emb,
    const float* __restrict__ rw1, const float* __restrict__ rb1,
    const float* __restrict__ rw2, const float* __restrict__ rb2,
    float* __restrict__ h, int N)
{
    __shared__ float s_w1[65 * 64];
    __shared__ float s_w2[64 * 64];
    __shared__ float s_x[8][66];
    __shared__ float s_y1[8][64];

    int tid = threadIdx.x;
    for (int i = tid; i < 65 * 64; i += 512) s_w1[i] = rw1[i];
    for (int i = tid; i < 64 * 64; i += 512) s_w2[i] = rw2[i];
    __syncthreads();

    int wv = tid >> 6;   // 0..7
    int c  = tid & 63;
    float b1 = rb1[c];
    float b2 = rb2[c];

    long stride = (long)gridDim.x * 8;
    for (long base = (long)blockIdx.x * 8; base < N; base += stride) {
        long node = base + wv;
        if (node >= N) continue;
        s_x[wv][c] = emb[(long)z[node] * HD + c];
        if (c == 0) s_x[wv][64] = t[node];
        float acc = b1;
        #pragma unroll
        for (int k = 0; k < 65; ++k)
            acc = fmaf(s_x[wv][k], s_w1[k * 64 + c], acc);
        s_y1[wv][c] = fmaxf(acc, 0.f);
        float acc2 = b2;
        #pragma unroll
        for (int k = 0; k < 64; ++k)
            acc2 = fmaf(s_y1[wv][k], s_w2[k * 64 + c], acc2);
        h[node * HD + c] = acc2;
    }
}

// ---------------------------------------------------------------------------
// fused layer (round-0 verified structure). One node per wave; 4 edges x
// 16 lanes x float4 aggregation; shfl_xor reduction; per-wave MLP with
// weights in LDS; NO block barriers in the node loop.
// CHANGE vs round-0: edge rows come from eap (CSR-slot order) -> the row
// address is just j, a pure sequential stream with no index dependency.
// Only the h[src] gather (L3-resident buffer) needs the sp[j] index load.
// ---------------------------------------------------------------------------
__global__ void __launch_bounds__(512, 6) layer_kernel(
    const int* __restrict__ offs,
    const int* __restrict__ sp,
    const float* __restrict__ h, const float* __restrict__ eap,
    const float* __restrict__ w1, const float* __restrict__ b1,
    const float* __restrict__ w2, const float* __restrict__ b2,
    float* __restrict__ out, int N, int relu_flag)
{
    __shared__ float s_w1[64 * 64];
    __shared__ float s_w2[64 * 64];
    __shared__ float s_x[8][64];
    __shared__ float s_y1[8][64];

    int tid = threadIdx.x;
    for (int i = tid; i < 64 * 64; i += 512) {
        s_w1[i] = w1[i];
        s_w2[i] = w2[i];
    }
    __syncthreads();

    int wv   = tid >> 6;        // wave in block: 0..7
    int lane = tid & 63;
    int c    = lane;            // channel (MLP phase)
    int eg   = lane >> 4;       // edge group 0..3
    int cq   = (lane & 15) * 4; // channel-quad base (agg phase)
    float bb1 = b1[c];
    float bb2 = b2[c];

    long stride = (long)gridDim.x * 8;
    for (long base = (long)blockIdx.x * 8; base < N; base += stride) {
        long node = base + wv;
        if (node >= N) continue;

        int jb = offs[node], je = offs[node + 1];
        float hval = h[node * HD + c];      // residual + self term

        float4 acc; acc.x = acc.y = acc.z = acc.w = 0.f;
        int j = jb + eg;
        int s = 0;
        if (j < je) s = sp[j];
        while (j < je) {
            const float4 av = *(const float4*)(eap + (long)j * HD + cq);
            const float4 hv = *(const float4*)(h   + (long)s * HD + cq);
            int jn = j + 4;
            int sn = 0;
            if (jn < je) sn = sp[jn];          // prefetch next src index
            acc.x += fmaxf(av.x + hv.x, 0.f);
            acc.y += fmaxf(av.y + hv.y, 0.f);
            acc.z += fmaxf(av.z + hv.z, 0.f);
            acc.w += fmaxf(av.w + hv.w, 0.f);
            j = jn; s = sn;
        }
        // reduce the 4 edge groups (lanes l, l^16, l^32, l^48 share cq)
        #pragma unroll
        for (int m = 16; m <= 32; m <<= 1) {
            acc.x += __shfl_xor(acc.x, m, 64);
            acc.y += __shfl_xor(acc.y, m, 64);
            acc.z += __shfl_xor(acc.z, m, 64);
            acc.w += __shfl_xor(acc.w, m, 64);
        }
        if (lane < 16) *(float4*)&s_x[wv][cq] = acc;
        // add self term (agg = sum + h[n]); in-wave LDS ordering via waitcnt
        s_x[wv][c] += hval;

        float a1 = bb1;
        #pragma unroll
        for (int k = 0; k < 64; ++k)
            a1 = fmaf(s_x[wv][k], s_w1[k * 64 + c], a1);
        s_y1[wv][c] = fmaxf(a1, 0.f);

        float a2 = bb2;
        #pragma unroll
        for (int k = 0; k < 64; ++k)
            a2 = fmaf(s_y1[wv][k], s_w2[k * 64 + c], a2);
        if (relu_flag) a2 = fmaxf(a2, 0.f);
        out[node * HD + c] = a2 + hval;
    }
}

// ---------------------------------------------------------------------------
extern "C" void kernel_launch(void* const* d_in, const int* in_sizes, int n_in,
                              void* d_out, int out_size, void* d_ws, size_t ws_size,
                              hipStream_t stream)
{
    const int*   z    = (const int*)  d_in[0];
    const int*   ei   = (const int*)  d_in[1];
    const float* ea   = (const float*)d_in[2];
    const float* t    = (const float*)d_in[3];
    const float* emb  = (const float*)d_in[4];
    const float* rw1  = (const float*)d_in[5];
    const float* rb1  = (const float*)d_in[6];
    const float* rw2  = (const float*)d_in[7];
    const float* rb2  = (const float*)d_in[8];
    const float* cw1  = (const float*)d_in[9];
    const float* cb1  = (const float*)d_in[10];
    const float* cw2  = (const float*)d_in[11];
    const float* cb2  = (const float*)d_in[12];

    int  N = in_sizes[0];
    long E = (long)in_sizes[1] / 2;
    const int* src = ei;        // edge_index[0]
    const int* dst = ei + E;    // edge_index[1]

    float* out = (float*)d_out;

    // workspace layout (eap first for alignment; total ~450MB)
    float* eap    = (float*)d_ws;                 // E*HD floats (410MB)
    float* bufA   = eap + (long)E * HD;           // N*HD floats
    int*   offs   = (int*)(bufA + (long)N * HD);  // N+1
    int*   cursor = offs + (N + 1);               // N
    int*   perm   = cursor + N;                   // E
    int*   sp     = perm + E;                     // E
    int*   bsum   = sp + E;                       // nb
    int    nb     = (N + 255) / 256;
    int*   bpre   = bsum + nb;                    // nb

    // --- build CSR-by-dst index ---
    zero_int_kernel<<<256, 256, 0, stream>>>(cursor, N);
    hist_kernel<<<2048, 256, 0, stream>>>(dst, cursor, E);
    blocksum_kernel<<<nb, 256, 0, stream>>>(cursor, bsum, N);
    scan2_kernel<<<1, 512, 0, stream>>>(bsum, bpre, offs, nb, N, (int)E);
    scan3_kernel<<<nb, 256, 0, stream>>>(cursor, bpre, offs, cursor, N);
    fill_kernel<<<2048, 256, 0, stream>>>(src, dst, cursor, perm, sp, E);

    // --- permute edge_attr into CSR order (once; layers then stream it) ---
    permute_ea_kernel<<<2048, 256, 0, stream>>>(perm, ea, eap, E);

    // --- h0 = init MLP ---
    node_init_kernel<<<1024, 512, 0, stream>>>(z, t, emb, rw1, rb1, rw2, rb2,
                                               bufA, N);

    // --- 3 GINE layers, ping-pong bufA <-> d_out ---
    float* hcur = bufA;
    for (int li = 0; li < 3; ++li) {
        float* hout = (li == 1) ? bufA : out;  // d_out, bufA, d_out
        layer_kernel<<<1024, 512, 0, stream>>>(
            offs, sp, hcur, eap,
            cw1 + (long)li * HD * HD, cb1 + (long)li * HD,
            cw2 + (long)li * HD * HD, cb2 + (long)li * HD,
            hout, N, (li < 2) ? 1 : 0);
        hcur = hout;
    }
}